// Round 15
// baseline (144.150 us; speedup 1.0000x reference)
//
#include <hip/hip_runtime.h>
#include <hip/hip_bf16.h>

#define NCLS 16
#define NBOX 2048
#define NTOT (NCLS * NBOX)
#define NCHUNK 32                 /* NBOX / 64 */
#define SCORE_THRESH 0.05f
#define NMS_THRESH 0.5f
#define DETS_PER_IMG 100
#define TOPC 128                  /* per-class candidate capacity (>=100) */
#define BBOX_CLIP 4.135166556742356f  /* log(1000/16) */

typedef unsigned long long u64;

__device__ __forceinline__ u64 sel_mx(u64 a, u64 b, bool keepmax) {
    u64 mx = (a > b) ? a : b;
    u64 mn = (a > b) ? b : a;
    return keepmax ? mx : mn;
}

// ============ Kernel A: fused decode + rank-merge sort + IoU bitmask ========
// R14 structure with the run-halving lever applied once more: 4 runs x 512
// (was 8 x 256). Rank probes: 2 keys x 4 runs x 10 guarded probes = 80
// DS/thread (was 144, -44%). Construction: canonical bitonic network
// truncated after stage k=512 — in-wave stages k<=128 use the ORIGINAL
// direction flag ((p&k)==0); k=256 needs one cross-wave LDS exchange
// (j=128) + register finish; k=512 needs two (j=256, j=128) + register
// finish, with the final stage forced all-descending (merge direction is
// free on bitonic input). Ping-pong run buffers (runsA aliased into boxu,
// runsB separate) avoid read-back hazard barriers: 4 syncs in the merge.
// Final runs live in runsB (non-aliased) so the rank search never races
// the box scatter. Sort is comparison-exact on distinct keys -> identical
// permutation -> bit-identical downstream. LDS 80 KB (proven OK in R9;
// occupancy is fixed at 1 block/CU by grid==256 regardless).
__global__ __launch_bounds__(1024) void sortmask_kernel(
    const float* __restrict__ logits,   // (NTOT, 2)
    const float* __restrict__ regr,     // (NTOT, 8)
    const float* __restrict__ props,    // (NBOX, 4)
    float4* __restrict__ dec,           // (NTOT)
    u64* __restrict__ keys_out,         // (NTOT)
    u64* __restrict__ maskT)            // (NCLS, NCHUNK, NBOX)
{
    int blk = blockIdx.x;
    int c = blk >> 4;
    int p = blk & 15;
    int tid = threadIdx.x;

    int w = tid >> 6, l = tid & 63;
    int p0 = w * 128 + l;
    int p1 = p0 + 64;
    __shared__ float4 decv[NBOX];   // 32 KB decoded boxes, original index
    __shared__ float4 boxu[NBOX];   // 32 KB sorted boxes; first 16 KB = runsA
    __shared__ u64 runsB[NBOX];     // 16 KB ping-pong / final runs
    u64* runsA = (u64*)boxu;        // aliased scratch (dead before box)
    float4* box = boxu;

    // ---- decode elements p0, p1 (identical math to reference) ----
    u64 e01[2];
#pragma unroll
    for (int s = 0; s < 2; s++) {
#pragma clang fp contract(off)
        int t = s ? p1 : p0;
        int i = c * NBOX + t;
        float x0 = logits[2 * i + 0];
        float x1 = logits[2 * i + 1];
        float m = fmaxf(x0, x1);
        float e0f = expf(x0 - m);
        float e1f = expf(x1 - m);
        float score = e1f / (e0f + e1f);

        float px1 = props[4 * t + 0];
        float py1 = props[4 * t + 1];
        float px2 = props[4 * t + 2];
        float py2 = props[4 * t + 3];

        float bw = px2 - px1 + 1.0f;
        float bh = py2 - py1 + 1.0f;
        float cx = px1 + 0.5f * bw;
        float cy = py1 + 0.5f * bh;

        float dx = regr[8 * i + 4] / 10.0f;
        float dy = regr[8 * i + 5] / 10.0f;
        float dw = fminf(regr[8 * i + 6] / 5.0f, BBOX_CLIP);
        float dh = fminf(regr[8 * i + 7] / 5.0f, BBOX_CLIP);

        float pcx = dx * bw + cx;
        float pcy = dy * bh + cy;
        float pw  = expf(dw) * bw;
        float ph  = expf(dh) * bh;

        float b0 = pcx - 0.5f * pw;
        float b1 = pcy - 0.5f * ph;
        float b2 = pcx + 0.5f * pw - 1.0f;
        float b3 = pcy + 0.5f * ph - 1.0f;

        b0 = fminf(fmaxf(b0, 0.0f), 1332.0f);
        b1 = fminf(fmaxf(b1, 0.0f), 799.0f);
        b2 = fminf(fmaxf(b2, 0.0f), 1332.0f);
        b3 = fminf(fmaxf(b3, 0.0f), 799.0f);

        float4 bb = make_float4(b0, b1, b2, b3);
        decv[t] = bb;
        if (p == 0) dec[i] = bb;      // single writer for downstream

        unsigned mono = 0u;
        if (score > SCORE_THRESH) mono = __float_as_uint(score) | 0x80000000u;
        e01[s] = ((u64)mono << 32) | (u64)(unsigned)(NBOX - 1 - t);
    }
    u64 e0 = e01[0], e1 = e01[1];

    // ---- stages k=2..128: in-wave (canonical directions, verbatim R1) ----
#pragma unroll
    for (int k = 2; k <= 128; k <<= 1) {
        bool d0 = ((p0 & k) == 0);
        bool d1 = ((p1 & k) == 0);   // differs from d0 only at k==64
#pragma unroll
        for (int j = k >> 1; j > 0; j >>= 1) {
            if (j == 64) {
                u64 mx = (e0 > e1) ? e0 : e1;
                u64 mn = (e0 > e1) ? e1 : e0;
                e0 = d0 ? mx : mn;
                e1 = d0 ? mn : mx;
            } else {
                u64 q0 = __shfl_xor(e0, j);
                u64 q1 = __shfl_xor(e1, j);
                bool hi = (l & j) != 0;
                e0 = sel_mx(e0, q0, d0 ^ hi);
                e1 = sel_mx(e1, q1, d1 ^ hi);
            }
        }
    }

    runsA[p0] = e0; runsA[p1] = e1;
    __syncthreads();

    // ---- stage k=256: j=128 via LDS, then j<=64 in-wave ----
    {
        bool d = ((p0 & 256) == 0);      // block direction (same for p1)
        u64 q0 = runsA[p0 ^ 128];
        u64 q1 = runsA[p1 ^ 128];
        bool hi = (p0 & 128) != 0;
        e0 = sel_mx(e0, q0, d ^ hi);
        e1 = sel_mx(e1, q1, d ^ hi);
        u64 mx = (e0 > e1) ? e0 : e1;    // j=64 in-thread
        u64 mn = (e0 > e1) ? e1 : e0;
        e0 = d ? mx : mn;
        e1 = d ? mn : mx;
#pragma unroll
        for (int j = 32; j > 0; j >>= 1) {
            u64 s0 = __shfl_xor(e0, j);
            u64 s1 = __shfl_xor(e1, j);
            bool h2 = (l & j) != 0;
            e0 = sel_mx(e0, s0, d ^ h2);
            e1 = sel_mx(e1, s1, d ^ h2);
        }
    }
    runsB[p0] = e0; runsB[p1] = e1;
    __syncthreads();

    // ---- stage k=512 (all-descending): j=256 via LDS ----
    {
        u64 q0 = runsB[p0 ^ 256];
        u64 q1 = runsB[p1 ^ 256];
        bool hi = (p0 & 256) != 0;
        e0 = sel_mx(e0, q0, !hi);
        e1 = sel_mx(e1, q1, !hi);
    }
    runsA[p0] = e0; runsA[p1] = e1;
    __syncthreads();

    // ---- k=512: j=128 via LDS, then j<=64 in-wave ----
    {
        u64 q0 = runsA[p0 ^ 128];
        u64 q1 = runsA[p1 ^ 128];
        bool hi = (p0 & 128) != 0;
        e0 = sel_mx(e0, q0, !hi);
        e1 = sel_mx(e1, q1, !hi);
        u64 mx = (e0 > e1) ? e0 : e1;    // j=64, descending
        u64 mn = (e0 > e1) ? e1 : e0;
        e0 = mx; e1 = mn;
#pragma unroll
        for (int j = 32; j > 0; j >>= 1) {
            u64 s0 = __shfl_xor(e0, j);
            u64 s1 = __shfl_xor(e1, j);
            bool h2 = (l & j) != 0;
            e0 = sel_mx(e0, s0, !h2);
            e1 = sel_mx(e1, s1, !h2);
        }
    }
    runsB[p0] = e0; runsB[p1] = e1;      // final 4 descending 512-runs
    __syncthreads();

    // ---- global ranks: sum over 4 runs of count(elements > key) ----
    // Guarded 10-step binary count (count can reach 512); own run's count
    // equals own position automatically (distinct keys).
    int rank0 = 0, rank1 = 0;
#pragma unroll
    for (int Rr = 0; Rr < 4; Rr++) {
        const u64* run = runsB + Rr * 512;
        int pa = 0, pb = 0;
#pragma unroll
        for (int step = 512; step >= 1; step >>= 1) {
            int qa = pa + step - 1;
            int qb = pb + step - 1;
            u64 va = run[qa & 511];
            u64 vb = run[qb & 511];
            if (qa < 512 && va > e0) pa += step;
            if (qb < 512 && vb > e1) pb += step;
        }
        rank0 += pa;
        rank1 += pb;
    }

    // ---- gather decoded boxes; emit sorted keys (p==0, scattered) ----
    // box scatter overwrites runsA's region only (boxu); final runs are in
    // runsB (non-aliased), and the last runsA reads were already fenced by
    // the sync after the k=512/j=128 exchange — no extra barrier needed.
    int i0 = (NBOX - 1) - (int)(e0 & 0xFFFFFFFFull);
    int i1 = (NBOX - 1) - (int)(e1 & 0xFFFFFFFFull);
    float4 g0 = decv[i0];
    float4 g1 = decv[i1];
    if (p == 0) {
        keys_out[c * NBOX + rank0] = e0;
        keys_out[c * NBOX + rank1] = e1;
    }
    box[rank0] = g0;
    box[rank1] = g1;
    __syncthreads();                 // box ready for mask phase

    // ---- mask phase (verbatim; division-free, bit-exact) ----
    int r = tid & 63;   // column lane
    int g = tid >> 6;   // wave id 0..15 = row-chunk group

    for (int pass = 0; pass < 2; pass++) {
#pragma clang fp contract(off)
        int Jc = pass ? (31 - p) : p;     // column chunk (balanced pairing)
        int j = Jc * 64 + r;              // global sorted column index
        float4 jb = box[j];
        float jar = (jb.z - jb.x) * (jb.w - jb.y);
        float hj = 0.5f * jar;
        float colC = hj + 5e-13f;

        for (int I = g; I <= Jc; I += 16) {
            u64 wm = 0;
            int rbase = I * 64;
#pragma unroll
            for (int i2 = 0; i2 < 64; i2++) {
#pragma clang fp contract(off)
                int gi = rbase + i2;
                float4 rb = box[gi];          // wave-uniform -> LDS broadcast
                float ar = (rb.z - rb.x) * (rb.w - rb.y);
                float rha = 0.5f * ar;
                float lx = fmaxf(rb.x, jb.x);
                float ly = fmaxf(rb.y, jb.y);
                float rx = fminf(rb.z, jb.z);
                float ry = fminf(rb.w, jb.w);
                float ww = fmaxf(rx - lx, 0.0f);
                float hh = fmaxf(ry - ly, 0.0f);
                float inter = ww * hh;        // identical to reference
                float s  = rha + colC;
                float band = 2e-6f * s;
                float delta = fmaf(1.5f, inter, -s);
                bool over = delta > band;
                bool amb = fabsf(delta) <= band;
                if (__any(amb)) {
                    float un = ar + jar - inter + 1e-12f;
                    float iou = inter / un;
                    bool ovx = iou > NMS_THRESH;
                    over = amb ? ovx : over;
                }
                if (over) wm |= 1ull << i2;
            }
            if (I == Jc) wm &= (1ull << r) - 1ull;   // gi<j on the diagonal
            maskT[((size_t)c * NCHUNK + I) * NBOX + j] = wm;
        }
    }
}

// ============ Kernel B: greedy resolve (VERBATIM — proven no-spill) ========
// One 64-lane wave per class; zero barriers, zero LDS. Lane l owns sorted
// columns {J*64+l : J}; suppression state = one bit per chunk J in `sup`.
//   * FULL unroll of the chunk loop, ping-pong tm[2][31] with compile-time
//     indices only (static indexing -> registers, never scratch).
//   * Iteration I issues row I+1's loads, greedies row I, consumes row I.
//   * sched_barrier(0) pins the loads above the greedy.
// R8+R13 lesson (twice confirmed): fusing ANY post-loop phase into this
// kernel makes regalloc cap VGPRs at 112 (< the 124 tm needs) and spill,
// regardless of launch_bounds. Keep it isolated.
__global__ __launch_bounds__(64) void resolve_kernel(
    const u64* __restrict__ keys,
    const u64* __restrict__ maskT,
    unsigned* __restrict__ keepbits,
    unsigned* __restrict__ compact,   // (NCLS, TOPC) sorted kept monos
    int* __restrict__ nkept)          // (NCLS)
{
    int c = blockIdx.x;
    int l = threadIdx.x;
    const u64* MT = maskT + (size_t)c * NCHUNK * NBOX;
    const u64* K  = keys + (size_t)c * NBOX;

    unsigned sup = 0;
    int offset = 0;                   // running kept count (wave-uniform)
    u64 tm[2][NCHUNK - 1];

    // prologue: row 0 tails (J=1..31) + row 0 diag + keys
#pragma unroll
    for (int t = 0; t < NCHUNK - 1; t++)
        tm[0][t] = MT[(size_t)(1 + t) * 64 + l];
    u64 diag = MT[l];
    u64 key  = K[l];

#pragma unroll
    for (int I = 0; I < NCHUNK; I++) {
        // ---- prefetch row I+1: tails (J=I+2..31) + diag + key ----
        u64 diagN = diag, keyN = key;
        if (I + 1 < NCHUNK) {
            const u64* rowpN = MT + (size_t)(I + 1) * NBOX + l;
#pragma unroll
            for (int t = 0; t < NCHUNK - 2 - I; t++)
                tm[(I + 1) & 1][t] = rowpN[(size_t)(I + 2 + t) * 64];
            diagN = MT[(size_t)(I + 1) * NBOX + (size_t)(I + 1) * 64 + l];
            keyN  = K[(I + 1) * 64 + l];
        }
        __builtin_amdgcn_sched_barrier(0);   // loads stay issued above greedy

        // ---- fixed-point greedy on row I (diag/key loaded last iteration) ----
        unsigned mono = (unsigned)(key >> 32);
        bool av = (mono != 0u) && (((sup >> I) & 1u) == 0u);
        u64 kept = 0;
        u64 availB = __ballot(av);
        while (availB) {
            u64 front = __ballot(av && ((diag & availB) == 0ull));
            kept |= front;
            bool fr = ((front >> l) & 1ull) != 0ull;
            bool sp = ((diag & front) != 0ull);   // suppressed by a new keeper
            av = av && !fr && !sp;
            availB = __ballot(av);
        }

        // ---- emit row I keep decisions ----
        int idx = (NBOX - 1) - (int)(key & 0xFFFFFFFFull);
        bool isk = ((kept >> l) & 1ull) != 0ull;
        keepbits[c * NBOX + idx] = isk ? (mono & 0x7FFFFFFFu) : 0u;

        // ---- compact sorted kept monos (first TOPC per class) ----
        int pos = offset + __popcll(kept & ((1ull << l) - 1ull));
        if (isk && pos < TOPC) compact[c * TOPC + pos] = mono;
        offset += __popcll(kept);

        // ---- consume row I tails -> sup bits for J=I+1..31 ----
#pragma unroll
        for (int t = 0; t < NCHUNK - 1 - I; t++)
            sup |= (tm[I & 1][t] & kept) ? (1u << (I + 1 + t)) : 0u;

        diag = diagN;
        key  = keyN;
    }

    // zero-pad candidate tail; publish count
    for (int t = offset + l; t < TOPC; t += 64) compact[c * TOPC + t] = 0u;
    if (l == 0) nkept[c] = offset;
}

// ============ Kernel C: redundant select + output write (sync-free) =========
// 128 blocks x 256 threads. EVERY block redundantly computes the sorted-
// candidate bit-search select from compact/nkept (L2-hot, 8 KB) into
// block-local LDS — redundant compute in parallel costs the same wall time
// as one copy and needs NO cross-block coupling. Then each block writes its
// 256 output rows.
__global__ __launch_bounds__(256) void selectwrite_kernel(
    const unsigned* __restrict__ compact,
    const int* __restrict__ nkept,
    const unsigned* __restrict__ keepbits,
    const float4* __restrict__ dec,
    const int* __restrict__ ulabels,
    float* __restrict__ out)
{
    __shared__ unsigned ls[NCLS * TOPC];   // 8 KB
    __shared__ int s_stats[2];
    int tid = threadIdx.x;

    for (int t = tid; t < NCLS * TOPC; t += 256) ls[t] = compact[t];
    __syncthreads();

    if (tid < 64) {
        int l = tid;
        int n_c = (l < NCLS) ? nkept[l] : 0;
        int nd = n_c;
#pragma unroll
        for (int off = 32; off > 0; off >>= 1) nd += __shfl_down(nd, off);
        nd = __shfl(nd, 0);

        unsigned kth = 0u;
        if (nd > DETS_PER_IMG) {
            const unsigned* my = &ls[(l & 15) * TOPC];
            bool active = (l < NCLS);
            unsigned prefix = 0u;
            for (int bit = 31; bit >= 0; bit--) {
                unsigned cand = prefix | (1u << bit);
                int cnt = 0;
                if (active) {
                    if (my[TOPC - 1] >= cand) cnt = TOPC;
                    else {
                        int pos = 0;
#pragma unroll
                        for (int step = 64; step >= 1; step >>= 1)
                            if (my[pos + step - 1] >= cand) pos += step;
                        cnt = pos;
                    }
                }
#pragma unroll
                for (int off = 32; off > 0; off >>= 1) cnt += __shfl_down(cnt, off);
                cnt = __shfl(cnt, 0);
                if (cnt >= DETS_PER_IMG) prefix = cand;
            }
            kth = prefix & 0x7FFFFFFFu;   // strip mono top bit -> score bits
        }
        if (l == 0) { s_stats[0] = nd; s_stats[1] = (int)kth; }
    }
    __syncthreads();

    int n_det = s_stats[0];
    unsigned kth = (unsigned)s_stats[1];

    int i = blockIdx.x * 256 + tid;
    unsigned kb = keepbits[i];
    bool kf = kb && (n_det <= DETS_PER_IMG || kb >= kth);  // uint cmp == float cmp

    float4 b = dec[i];
    float* o5 = out + (size_t)i * 5;
    if (kf) {
        o5[0] = b.x; o5[1] = b.y; o5[2] = b.z; o5[3] = b.w;
        o5[4] = __uint_as_float(kb);
    } else {
        o5[0] = 0.0f; o5[1] = 0.0f; o5[2] = 0.0f; o5[3] = 0.0f; o5[4] = 0.0f;
    }

    int c = i >> 11;
    out[NTOT * 5 + i] = (float)ulabels[c];
    out[NTOT * 5 + NTOT + i] = kf ? 1.0f : 0.0f;
}

extern "C" void kernel_launch(void* const* d_in, const int* in_sizes, int n_in,
                              void* d_out, int out_size, void* d_ws, size_t ws_size,
                              hipStream_t stream) {
    (void)in_sizes; (void)n_in; (void)out_size; (void)ws_size;

    const float* class_logit    = (const float*)d_in[0];   // (NTOT,2)
    const float* box_regression = (const float*)d_in[1];   // (NTOT,8)
    const float* proposal_boxes = (const float*)d_in[2];   // (NBOX,4)
    const int*   unique_labels  = (const int*)d_in[3];     // (NCLS)

    char* ws = (char*)d_ws;
    float4* dec        = (float4*)(ws + 0);         // 524288
    u64* keys          = (u64*)(ws + 524288);       // 262144
    u64* maskT         = (u64*)(ws + 786432);       // 8388608
    unsigned* keepbits = (unsigned*)(ws + 9175040); // 131072
    unsigned* compact  = (unsigned*)(ws + 9306112); // 8192
    int* nkept         = (int*)(ws + 9314304);      // 64

    float* out = (float*)d_out;

    sortmask_kernel<<<NCLS * 16, 1024, 0, stream>>>(class_logit, box_regression,
                                                    proposal_boxes, dec, keys,
                                                    maskT);
    resolve_kernel<<<NCLS, 64, 0, stream>>>(keys, maskT, keepbits,
                                            compact, nkept);
    selectwrite_kernel<<<NTOT / 256, 256, 0, stream>>>(compact, nkept, keepbits,
                                                       dec, unique_labels, out);
}

// Round 16
// 132.176 us; speedup vs baseline: 1.0906x; 1.0906x over previous
//
#include <hip/hip_runtime.h>
#include <hip/hip_bf16.h>

#define NCLS 16
#define NBOX 2048
#define NTOT (NCLS * NBOX)
#define NCHUNK 32                 /* NBOX / 64 */
#define SCORE_THRESH 0.05f
#define NMS_THRESH 0.5f
#define DETS_PER_IMG 100
#define TOPC 128                  /* per-class candidate capacity (>=100) */
#define BBOX_CLIP 4.135166556742356f  /* log(1000/16) */

typedef unsigned long long u64;

__device__ __forceinline__ u64 sel_mx(u64 a, u64 b, bool keepmax) {
    u64 mx = (a > b) ? a : b;
    u64 mn = (a > b) ? b : a;
    return keepmax ? mx : mn;
}

// ============ Kernel A: fused decode + rank-merge sort + IoU bitmask ========
// VERBATIM R14 — measured best (44.7 us; total 132.8). 8 runs x 256.
// R15 lesson: pushing to 4 runs x 512 regressed to 72+ us — halving the
// independent search chains (16 -> 8) broke DS-latency hiding (VALUBusy
// 66 -> 40%) and the extra merge level's barriers re-serialized the block.
// The run-length lever is exhausted at 8 x 256.
__global__ __launch_bounds__(1024) void sortmask_kernel(
    const float* __restrict__ logits,   // (NTOT, 2)
    const float* __restrict__ regr,     // (NTOT, 8)
    const float* __restrict__ props,    // (NBOX, 4)
    float4* __restrict__ dec,           // (NTOT)
    u64* __restrict__ keys_out,         // (NTOT)
    u64* __restrict__ maskT)            // (NCLS, NCHUNK, NBOX)
{
    int blk = blockIdx.x;
    int c = blk >> 4;
    int p = blk & 15;
    int tid = threadIdx.x;

    int w = tid >> 6, l = tid & 63;
    int p0 = w * 128 + l;
    int p1 = p0 + 64;
    __shared__ float4 decv[NBOX];   // 32 KB decoded boxes, original index
    __shared__ float4 boxu[NBOX];   // 32 KB sorted boxes; first 16 KB = runs
    u64* runs = (u64*)boxu;         // 8 runs x 256 keys (dead before box)
    float4* box = boxu;

    // ---- decode elements p0, p1 (identical math to reference) ----
    u64 e01[2];
#pragma unroll
    for (int s = 0; s < 2; s++) {
#pragma clang fp contract(off)
        int t = s ? p1 : p0;
        int i = c * NBOX + t;
        float x0 = logits[2 * i + 0];
        float x1 = logits[2 * i + 1];
        float m = fmaxf(x0, x1);
        float e0f = expf(x0 - m);
        float e1f = expf(x1 - m);
        float score = e1f / (e0f + e1f);

        float px1 = props[4 * t + 0];
        float py1 = props[4 * t + 1];
        float px2 = props[4 * t + 2];
        float py2 = props[4 * t + 3];

        float bw = px2 - px1 + 1.0f;
        float bh = py2 - py1 + 1.0f;
        float cx = px1 + 0.5f * bw;
        float cy = py1 + 0.5f * bh;

        float dx = regr[8 * i + 4] / 10.0f;
        float dy = regr[8 * i + 5] / 10.0f;
        float dw = fminf(regr[8 * i + 6] / 5.0f, BBOX_CLIP);
        float dh = fminf(regr[8 * i + 7] / 5.0f, BBOX_CLIP);

        float pcx = dx * bw + cx;
        float pcy = dy * bh + cy;
        float pw  = expf(dw) * bw;
        float ph  = expf(dh) * bh;

        float b0 = pcx - 0.5f * pw;
        float b1 = pcy - 0.5f * ph;
        float b2 = pcx + 0.5f * pw - 1.0f;
        float b3 = pcy + 0.5f * ph - 1.0f;

        b0 = fminf(fmaxf(b0, 0.0f), 1332.0f);
        b1 = fminf(fmaxf(b1, 0.0f), 799.0f);
        b2 = fminf(fmaxf(b2, 0.0f), 1332.0f);
        b3 = fminf(fmaxf(b3, 0.0f), 799.0f);

        float4 bb = make_float4(b0, b1, b2, b3);
        decv[t] = bb;
        if (p == 0) dec[i] = bb;      // single writer for downstream

        unsigned mono = 0u;
        if (score > SCORE_THRESH) mono = __float_as_uint(score) | 0x80000000u;
        e01[s] = ((u64)mono << 32) | (u64)(unsigned)(NBOX - 1 - t);
    }
    u64 e0 = e01[0], e1 = e01[1];

    // ---- in-wave bitonic sort of 128 elements ----
    // Even waves descending, odd waves ascending (inputs to the 256-merge).
    bool flip = (w & 1) != 0;
#pragma unroll
    for (int k = 2; k <= 128; k <<= 1) {
        bool d0 = (((l & k) == 0) != flip);
        bool d1 = ((((l + 64) & k) == 0) != flip);
#pragma unroll
        for (int j = k >> 1; j > 0; j >>= 1) {
            if (j == 64) {
                u64 mx = (e0 > e1) ? e0 : e1;
                u64 mn = (e0 > e1) ? e1 : e0;
                e0 = d0 ? mx : mn;
                e1 = d0 ? mn : mx;
            } else {
                u64 q0 = __shfl_xor(e0, j);
                u64 q1 = __shfl_xor(e1, j);
                bool hi = (l & j) != 0;
                e0 = sel_mx(e0, q0, d0 ^ hi);
                e1 = sel_mx(e1, q1, d1 ^ hi);
            }
        }
    }

    // ---- publish pre-merge halves (desc half 0, asc half 1 per run) ----
    int R = w >> 1;                  // run id 0..7
    int half = (w & 1) * 128;        // this wave's half within the run
    runs[R * 256 + half + l] = e0;
    runs[R * 256 + half + 64 + l] = e1;
    __syncthreads();

    // ---- 256-merge step j=128 via LDS: max -> lower half (descending) ----
    {
        u64 pa0 = runs[R * 256 + (half ^ 128) + l];
        u64 pa1 = runs[R * 256 + (half ^ 128) + 64 + l];
        if (half == 0) {
            e0 = (e0 > pa0) ? e0 : pa0;           // keep max at low half
            e1 = (e1 > pa1) ? e1 : pa1;
        } else {
            e0 = (pa0 > e0) ? e0 : pa0;           // keep min at high half
            e1 = (pa1 > e1) ? e1 : pa1;
        }
    }
    __syncthreads();                 // all partner reads done before rewrite

    // ---- finish descending merge of this wave's 128: j=64 then j=32..1 ----
    {
        u64 mx = (e0 > e1) ? e0 : e1;
        u64 mn = (e0 > e1) ? e1 : e0;
        e0 = mx; e1 = mn;
    }
#pragma unroll
    for (int j = 32; j > 0; j >>= 1) {
        u64 q0 = __shfl_xor(e0, j);
        u64 q1 = __shfl_xor(e1, j);
        bool hi = (l & j) != 0;
        e0 = sel_mx(e0, q0, !hi);
        e1 = sel_mx(e1, q1, !hi);
    }

    // ---- write final descending 256-runs ----
    runs[R * 256 + half + l] = e0;
    runs[R * 256 + half + 64 + l] = e1;
    __syncthreads();

    // ---- global ranks: sum over 8 runs of count(elements > key) ----
    // Guarded 9-step binary count (count can reach 256); own run's count
    // equals own position automatically (distinct keys).
    int rank0 = 0, rank1 = 0;
#pragma unroll
    for (int Rr = 0; Rr < 8; Rr++) {
        const u64* run = runs + Rr * 256;
        int pa = 0, pb = 0;
#pragma unroll
        for (int step = 256; step >= 1; step >>= 1) {
            int qa = pa + step - 1;
            int qb = pb + step - 1;
            u64 va = run[qa & 255];
            u64 vb = run[qb & 255];
            if (qa < 256 && va > e0) pa += step;
            if (qb < 256 && vb > e1) pb += step;
        }
        rank0 += pa;
        rank1 += pb;
    }

    // ---- gather decoded boxes; emit sorted keys (p==0, scattered) ----
    int i0 = (NBOX - 1) - (int)(e0 & 0xFFFFFFFFull);
    int i1 = (NBOX - 1) - (int)(e1 & 0xFFFFFFFFull);
    float4 g0 = decv[i0];
    float4 g1 = decv[i1];
    if (p == 0) {
        keys_out[c * NBOX + rank0] = e0;
        keys_out[c * NBOX + rank1] = e1;
    }
    __syncthreads();                 // all runs/decv reads done before alias
    box[rank0] = g0;
    box[rank1] = g1;
    __syncthreads();                 // box ready for mask phase

    // ---- mask phase (verbatim; division-free, bit-exact) ----
    int r = tid & 63;   // column lane
    int g = tid >> 6;   // wave id 0..15 = row-chunk group

    for (int pass = 0; pass < 2; pass++) {
#pragma clang fp contract(off)
        int Jc = pass ? (31 - p) : p;     // column chunk (balanced pairing)
        int j = Jc * 64 + r;              // global sorted column index
        float4 jb = box[j];
        float jar = (jb.z - jb.x) * (jb.w - jb.y);
        float hj = 0.5f * jar;
        float colC = hj + 5e-13f;

        for (int I = g; I <= Jc; I += 16) {
            u64 wm = 0;
            int rbase = I * 64;
#pragma unroll
            for (int i2 = 0; i2 < 64; i2++) {
#pragma clang fp contract(off)
                int gi = rbase + i2;
                float4 rb = box[gi];          // wave-uniform -> LDS broadcast
                float ar = (rb.z - rb.x) * (rb.w - rb.y);
                float rha = 0.5f * ar;
                float lx = fmaxf(rb.x, jb.x);
                float ly = fmaxf(rb.y, jb.y);
                float rx = fminf(rb.z, jb.z);
                float ry = fminf(rb.w, jb.w);
                float ww = fmaxf(rx - lx, 0.0f);
                float hh = fmaxf(ry - ly, 0.0f);
                float inter = ww * hh;        // identical to reference
                float s  = rha + colC;
                float band = 2e-6f * s;
                float delta = fmaf(1.5f, inter, -s);
                bool over = delta > band;
                bool amb = fabsf(delta) <= band;
                if (__any(amb)) {
                    float un = ar + jar - inter + 1e-12f;
                    float iou = inter / un;
                    bool ovx = iou > NMS_THRESH;
                    over = amb ? ovx : over;
                }
                if (over) wm |= 1ull << i2;
            }
            if (I == Jc) wm &= (1ull << r) - 1ull;   // gi<j on the diagonal
            maskT[((size_t)c * NCHUNK + I) * NBOX + j] = wm;
        }
    }
}

// ============ Kernel B: greedy resolve (VERBATIM — proven no-spill) ========
// One 64-lane wave per class; zero barriers, zero LDS. Lane l owns sorted
// columns {J*64+l : J}; suppression state = one bit per chunk J in `sup`.
//   * FULL unroll of the chunk loop, ping-pong tm[2][31] with compile-time
//     indices only (static indexing -> registers, never scratch).
//   * Iteration I issues row I+1's loads, greedies row I, consumes row I.
//   * sched_barrier(0) pins the loads above the greedy.
// R8+R13 lesson (twice confirmed): fusing ANY post-loop phase into this
// kernel makes regalloc cap VGPRs at 112 (< the 124 tm needs) and spill,
// regardless of launch_bounds. Keep it isolated.
__global__ __launch_bounds__(64) void resolve_kernel(
    const u64* __restrict__ keys,
    const u64* __restrict__ maskT,
    unsigned* __restrict__ keepbits,
    unsigned* __restrict__ compact,   // (NCLS, TOPC) sorted kept monos
    int* __restrict__ nkept)          // (NCLS)
{
    int c = blockIdx.x;
    int l = threadIdx.x;
    const u64* MT = maskT + (size_t)c * NCHUNK * NBOX;
    const u64* K  = keys + (size_t)c * NBOX;

    unsigned sup = 0;
    int offset = 0;                   // running kept count (wave-uniform)
    u64 tm[2][NCHUNK - 1];

    // prologue: row 0 tails (J=1..31) + row 0 diag + keys
#pragma unroll
    for (int t = 0; t < NCHUNK - 1; t++)
        tm[0][t] = MT[(size_t)(1 + t) * 64 + l];
    u64 diag = MT[l];
    u64 key  = K[l];

#pragma unroll
    for (int I = 0; I < NCHUNK; I++) {
        // ---- prefetch row I+1: tails (J=I+2..31) + diag + key ----
        u64 diagN = diag, keyN = key;
        if (I + 1 < NCHUNK) {
            const u64* rowpN = MT + (size_t)(I + 1) * NBOX + l;
#pragma unroll
            for (int t = 0; t < NCHUNK - 2 - I; t++)
                tm[(I + 1) & 1][t] = rowpN[(size_t)(I + 2 + t) * 64];
            diagN = MT[(size_t)(I + 1) * NBOX + (size_t)(I + 1) * 64 + l];
            keyN  = K[(I + 1) * 64 + l];
        }
        __builtin_amdgcn_sched_barrier(0);   // loads stay issued above greedy

        // ---- fixed-point greedy on row I (diag/key loaded last iteration) ----
        unsigned mono = (unsigned)(key >> 32);
        bool av = (mono != 0u) && (((sup >> I) & 1u) == 0u);
        u64 kept = 0;
        u64 availB = __ballot(av);
        while (availB) {
            u64 front = __ballot(av && ((diag & availB) == 0ull));
            kept |= front;
            bool fr = ((front >> l) & 1ull) != 0ull;
            bool sp = ((diag & front) != 0ull);   // suppressed by a new keeper
            av = av && !fr && !sp;
            availB = __ballot(av);
        }

        // ---- emit row I keep decisions ----
        int idx = (NBOX - 1) - (int)(key & 0xFFFFFFFFull);
        bool isk = ((kept >> l) & 1ull) != 0ull;
        keepbits[c * NBOX + idx] = isk ? (mono & 0x7FFFFFFFu) : 0u;

        // ---- compact sorted kept monos (first TOPC per class) ----
        int pos = offset + __popcll(kept & ((1ull << l) - 1ull));
        if (isk && pos < TOPC) compact[c * TOPC + pos] = mono;
        offset += __popcll(kept);

        // ---- consume row I tails -> sup bits for J=I+1..31 ----
#pragma unroll
        for (int t = 0; t < NCHUNK - 1 - I; t++)
            sup |= (tm[I & 1][t] & kept) ? (1u << (I + 1 + t)) : 0u;

        diag = diagN;
        key  = keyN;
    }

    // zero-pad candidate tail; publish count
    for (int t = offset + l; t < TOPC; t += 64) compact[c * TOPC + t] = 0u;
    if (l == 0) nkept[c] = offset;
}

// ============ Kernel C: redundant select + output write (sync-free) =========
// 128 blocks x 256 threads. EVERY block redundantly computes the sorted-
// candidate bit-search select from compact/nkept (L2-hot, 8 KB) into
// block-local LDS — redundant compute in parallel costs the same wall time
// as one copy and needs NO cross-block coupling. Then each block writes its
// 256 output rows.
__global__ __launch_bounds__(256) void selectwrite_kernel(
    const unsigned* __restrict__ compact,
    const int* __restrict__ nkept,
    const unsigned* __restrict__ keepbits,
    const float4* __restrict__ dec,
    const int* __restrict__ ulabels,
    float* __restrict__ out)
{
    __shared__ unsigned ls[NCLS * TOPC];   // 8 KB
    __shared__ int s_stats[2];
    int tid = threadIdx.x;

    for (int t = tid; t < NCLS * TOPC; t += 256) ls[t] = compact[t];
    __syncthreads();

    if (tid < 64) {
        int l = tid;
        int n_c = (l < NCLS) ? nkept[l] : 0;
        int nd = n_c;
#pragma unroll
        for (int off = 32; off > 0; off >>= 1) nd += __shfl_down(nd, off);
        nd = __shfl(nd, 0);

        unsigned kth = 0u;
        if (nd > DETS_PER_IMG) {
            const unsigned* my = &ls[(l & 15) * TOPC];
            bool active = (l < NCLS);
            unsigned prefix = 0u;
            for (int bit = 31; bit >= 0; bit--) {
                unsigned cand = prefix | (1u << bit);
                int cnt = 0;
                if (active) {
                    if (my[TOPC - 1] >= cand) cnt = TOPC;
                    else {
                        int pos = 0;
#pragma unroll
                        for (int step = 64; step >= 1; step >>= 1)
                            if (my[pos + step - 1] >= cand) pos += step;
                        cnt = pos;
                    }
                }
#pragma unroll
                for (int off = 32; off > 0; off >>= 1) cnt += __shfl_down(cnt, off);
                cnt = __shfl(cnt, 0);
                if (cnt >= DETS_PER_IMG) prefix = cand;
            }
            kth = prefix & 0x7FFFFFFFu;   // strip mono top bit -> score bits
        }
        if (l == 0) { s_stats[0] = nd; s_stats[1] = (int)kth; }
    }
    __syncthreads();

    int n_det = s_stats[0];
    unsigned kth = (unsigned)s_stats[1];

    int i = blockIdx.x * 256 + tid;
    unsigned kb = keepbits[i];
    bool kf = kb && (n_det <= DETS_PER_IMG || kb >= kth);  // uint cmp == float cmp

    float4 b = dec[i];
    float* o5 = out + (size_t)i * 5;
    if (kf) {
        o5[0] = b.x; o5[1] = b.y; o5[2] = b.z; o5[3] = b.w;
        o5[4] = __uint_as_float(kb);
    } else {
        o5[0] = 0.0f; o5[1] = 0.0f; o5[2] = 0.0f; o5[3] = 0.0f; o5[4] = 0.0f;
    }

    int c = i >> 11;
    out[NTOT * 5 + i] = (float)ulabels[c];
    out[NTOT * 5 + NTOT + i] = kf ? 1.0f : 0.0f;
}

extern "C" void kernel_launch(void* const* d_in, const int* in_sizes, int n_in,
                              void* d_out, int out_size, void* d_ws, size_t ws_size,
                              hipStream_t stream) {
    (void)in_sizes; (void)n_in; (void)out_size; (void)ws_size;

    const float* class_logit    = (const float*)d_in[0];   // (NTOT,2)
    const float* box_regression = (const float*)d_in[1];   // (NTOT,8)
    const float* proposal_boxes = (const float*)d_in[2];   // (NBOX,4)
    const int*   unique_labels  = (const int*)d_in[3];     // (NCLS)

    char* ws = (char*)d_ws;
    float4* dec        = (float4*)(ws + 0);         // 524288
    u64* keys          = (u64*)(ws + 524288);       // 262144
    u64* maskT         = (u64*)(ws + 786432);       // 8388608
    unsigned* keepbits = (unsigned*)(ws + 9175040); // 131072
    unsigned* compact  = (unsigned*)(ws + 9306112); // 8192
    int* nkept         = (int*)(ws + 9314304);      // 64

    float* out = (float*)d_out;

    sortmask_kernel<<<NCLS * 16, 1024, 0, stream>>>(class_logit, box_regression,
                                                    proposal_boxes, dec, keys,
                                                    maskT);
    resolve_kernel<<<NCLS, 64, 0, stream>>>(keys, maskT, keepbits,
                                            compact, nkept);
    selectwrite_kernel<<<NTOT / 256, 256, 0, stream>>>(compact, nkept, keepbits,
                                                       dec, unique_labels, out);
}